// Round 1
// baseline (487.493 us; speedup 1.0000x reference)
//
#include <hip/hip_runtime.h>
#include <hip/hip_bf16.h>

#define NNODES 50000
#define NEDGES 800000
#define IN_DIM 128
#define EDGE_DIM 32
#define OUT_DIM 128
#define KDIM 160          // IN_DIM + EDGE_DIM
#define A_STRIDE 168      // 160 + 8 pad: kills 8-way LDS bank conflict, keeps 16B align
#define NS 136            // 128 + 8 pad for node kernel

typedef __attribute__((ext_vector_type(8))) short short8;
typedef __attribute__((ext_vector_type(4))) short short4v;
typedef __attribute__((ext_vector_type(4))) float floatx4;

__device__ __forceinline__ short f2bf(float f) {
    union { float f; unsigned u; } v; v.f = f;
    unsigned r = (v.u + 0x7FFFu + ((v.u >> 16) & 1u)) >> 16;  // round-nearest-even
    return (short)r;
}

__device__ __forceinline__ void store_bf4(short* p, floatx4 v) {
    short4v s;
    s.x = f2bf(v.x); s.y = f2bf(v.y); s.z = f2bf(v.z); s.w = f2bf(v.w);
    *(short4v*)p = s;
}

// ---------------------------------------------------------------------------
// Prep: WcatB[n][k] (k<128: W1 = W_ne[:, :128]; k>=128: W_comb = W2 @ W_edge),
//       WselfB[n][k] = W_self — both bf16, laid out so B-fragment reads are
//       contiguous (BT[n][k] row-major == weight[n][k]).
// ---------------------------------------------------------------------------
__global__ void prep_weights(const float* __restrict__ W_edge,   // [128][32]
                             const float* __restrict__ W_ne,     // [128][256]
                             const float* __restrict__ W_self,   // [128][128]
                             short* __restrict__ WcatB,          // [128][160]
                             short* __restrict__ WselfB)         // [128][128]
{
    int idx = blockIdx.x * 256 + threadIdx.x;
    if (idx < OUT_DIM * KDIM) {
        int n = idx / KDIM, k = idx - n * KDIM;
        float val;
        if (k < IN_DIM) {
            val = W_ne[n * 256 + k];
        } else {
            int j = k - IN_DIM;
            float s = 0.f;
            for (int kk = 0; kk < 128; ++kk)
                s += W_ne[n * 256 + 128 + kk] * W_edge[kk * 32 + j];
            val = s;
        }
        WcatB[idx] = f2bf(val);
    } else if (idx < OUT_DIM * KDIM + OUT_DIM * IN_DIM) {
        int s = idx - OUT_DIM * KDIM;
        WselfB[s] = f2bf(W_self[s]);
    }
}

// ---------------------------------------------------------------------------
// Edge kernel: per block, 64 edges x 128 outputs, K=160.
// m = relu(A @ Bt^T + b_ne); atomicMax (int view, values >= 0) into neigh.
// ---------------------------------------------------------------------------
__global__ __launch_bounds__(256) void edge_kernel(
    const float* __restrict__ nfeat, const float* __restrict__ etype,
    const int* __restrict__ src, const int* __restrict__ dst,
    const float* __restrict__ b_ne, const short* __restrict__ WcatB,
    float* __restrict__ neigh)
{
    __shared__ short As[64 * A_STRIDE];
    __shared__ short Bs[128 * A_STRIDE];
    const int tid = threadIdx.x;
    const int e0 = blockIdx.x * 64;

    // --- stage B (128 x 160 bf16, L2-hot) ---
    {
        int r = tid >> 1, h = tid & 1;
        const short8* g = (const short8*)(WcatB + r * KDIM + h * 80);
        short* l = Bs + r * A_STRIDE + h * 80;
        #pragma unroll
        for (int c = 0; c < 10; ++c)
            *(short8*)(l + 8 * c) = g[c];
    }
    // --- stage etype -> A cols 128..159 ---
    {
        const floatx4* ge = (const floatx4*)(etype + (size_t)e0 * 32);
        #pragma unroll
        for (int i = 0; i < 2; ++i) {
            int f = tid + i * 256;            // 512 float4 total
            int e = f >> 3, c = f & 7;
            store_bf4(As + e * A_STRIDE + IN_DIM + 4 * c, ge[f]);
        }
    }
    // --- stage gathered nfeat rows -> A cols 0..127 ---
    {
        int g = tid & 15, eo = tid >> 4;
        #pragma unroll
        for (int p = 0; p < 4; ++p) {
            int e = eo + p * 16;
            int s = src[e0 + e];              // same addr across 16 lanes
            const floatx4* row = (const floatx4*)(nfeat + (size_t)s * 128);
            floatx4 v0 = row[g];
            floatx4 v1 = row[g + 16];
            store_bf4(As + e * A_STRIDE + 4 * g, v0);
            store_bf4(As + e * A_STRIDE + 64 + 4 * g, v1);
        }
    }
    __syncthreads();

    const int lane = tid & 63;
    const int w = tid >> 6;
    const int et = w & 1;                     // edge half: rows et*32..+31
    const int nh = w >> 1;                    // out half: cols nh*64..+63
    const int li = lane & 15, q = lane >> 4;

    floatx4 acc[2][4];
    #pragma unroll
    for (int i = 0; i < 2; ++i)
        #pragma unroll
        for (int j = 0; j < 4; ++j)
            acc[i][j] = (floatx4){0.f, 0.f, 0.f, 0.f};

    const short* Ab = As + (et * 32 + li) * A_STRIDE + q * 8;
    const short* Bb = Bs + (nh * 64 + li) * A_STRIDE + q * 8;
    #pragma unroll
    for (int kk = 0; kk < 5; ++kk) {
        short8 a0 = *(const short8*)(Ab + kk * 32);
        short8 a1 = *(const short8*)(Ab + 16 * A_STRIDE + kk * 32);
        short8 b0 = *(const short8*)(Bb + kk * 32);
        short8 b1 = *(const short8*)(Bb + 16 * A_STRIDE + kk * 32);
        short8 b2 = *(const short8*)(Bb + 32 * A_STRIDE + kk * 32);
        short8 b3 = *(const short8*)(Bb + 48 * A_STRIDE + kk * 32);
        acc[0][0] = __builtin_amdgcn_mfma_f32_16x16x32_bf16(a0, b0, acc[0][0], 0, 0, 0);
        acc[0][1] = __builtin_amdgcn_mfma_f32_16x16x32_bf16(a0, b1, acc[0][1], 0, 0, 0);
        acc[0][2] = __builtin_amdgcn_mfma_f32_16x16x32_bf16(a0, b2, acc[0][2], 0, 0, 0);
        acc[0][3] = __builtin_amdgcn_mfma_f32_16x16x32_bf16(a0, b3, acc[0][3], 0, 0, 0);
        acc[1][0] = __builtin_amdgcn_mfma_f32_16x16x32_bf16(a1, b0, acc[1][0], 0, 0, 0);
        acc[1][1] = __builtin_amdgcn_mfma_f32_16x16x32_bf16(a1, b1, acc[1][1], 0, 0, 0);
        acc[1][2] = __builtin_amdgcn_mfma_f32_16x16x32_bf16(a1, b2, acc[1][2], 0, 0, 0);
        acc[1][3] = __builtin_amdgcn_mfma_f32_16x16x32_bf16(a1, b3, acc[1][3], 0, 0, 0);
    }

    // C/D layout: row = q*4 + reg, col = li (within each 16x16 tile)
    #pragma unroll
    for (int ta = 0; ta < 2; ++ta) {
        #pragma unroll
        for (int r = 0; r < 4; ++r) {
            int el = et * 32 + ta * 16 + q * 4 + r;
            int d = dst[e0 + el];
            int* nrow = (int*)neigh + (size_t)d * 128;
            #pragma unroll
            for (int tb = 0; tb < 4; ++tb) {
                int o = nh * 64 + tb * 16 + li;
                float v = acc[ta][tb][r] + b_ne[o];
                v = v > 0.f ? v : 0.f;
                // v >= 0: int compare == float compare; init 0 handles deg==0
                atomicMax(nrow + o, __float_as_int(v));
            }
        }
    }
}

// ---------------------------------------------------------------------------
// Node kernel: out = (1+eps)*neigh + nfeat @ W_self^T + b_self
// 64 nodes x 128 outputs per block, K=128.
// ---------------------------------------------------------------------------
__global__ __launch_bounds__(256) void node_kernel(
    const float* __restrict__ nfeat, const float* __restrict__ b_self,
    const float* __restrict__ eps, const short* __restrict__ WselfB,
    const float* __restrict__ neigh, float* __restrict__ out)
{
    __shared__ short As[64 * NS];
    __shared__ short Bs[128 * NS];
    const int tid = threadIdx.x;
    const int n0 = blockIdx.x * 64;

    {
        int r = tid >> 1, h = tid & 1;
        const short8* g = (const short8*)(WselfB + r * 128 + h * 64);
        short* l = Bs + r * NS + h * 64;
        #pragma unroll
        for (int c = 0; c < 8; ++c)
            *(short8*)(l + 8 * c) = g[c];
    }
    {
        int r = tid >> 2, fi = tid & 3;
        int n = n0 + r;
        if (n < NNODES) {
            const floatx4* row = (const floatx4*)(nfeat + (size_t)n * 128);
            #pragma unroll
            for (int p = 0; p < 8; ++p) {
                int f = fi + 4 * p;
                store_bf4(As + r * NS + 4 * f, row[f]);
            }
        } else {
            #pragma unroll
            for (int p = 0; p < 8; ++p) {
                int f = fi + 4 * p;
                *(short4v*)(As + r * NS + 4 * f) = (short4v){0, 0, 0, 0};
            }
        }
    }
    __syncthreads();

    const int lane = tid & 63;
    const int w = tid >> 6;
    const int et = w & 1;
    const int nh = w >> 1;
    const int li = lane & 15, q = lane >> 4;

    floatx4 acc[2][4];
    #pragma unroll
    for (int i = 0; i < 2; ++i)
        #pragma unroll
        for (int j = 0; j < 4; ++j)
            acc[i][j] = (floatx4){0.f, 0.f, 0.f, 0.f};

    const short* Ab = As + (et * 32 + li) * NS + q * 8;
    const short* Bb = Bs + (nh * 64 + li) * NS + q * 8;
    #pragma unroll
    for (int kk = 0; kk < 4; ++kk) {
        short8 a0 = *(const short8*)(Ab + kk * 32);
        short8 a1 = *(const short8*)(Ab + 16 * NS + kk * 32);
        short8 b0 = *(const short8*)(Bb + kk * 32);
        short8 b1 = *(const short8*)(Bb + 16 * NS + kk * 32);
        short8 b2 = *(const short8*)(Bb + 32 * NS + kk * 32);
        short8 b3 = *(const short8*)(Bb + 48 * NS + kk * 32);
        acc[0][0] = __builtin_amdgcn_mfma_f32_16x16x32_bf16(a0, b0, acc[0][0], 0, 0, 0);
        acc[0][1] = __builtin_amdgcn_mfma_f32_16x16x32_bf16(a0, b1, acc[0][1], 0, 0, 0);
        acc[0][2] = __builtin_amdgcn_mfma_f32_16x16x32_bf16(a0, b2, acc[0][2], 0, 0, 0);
        acc[0][3] = __builtin_amdgcn_mfma_f32_16x16x32_bf16(a0, b3, acc[0][3], 0, 0, 0);
        acc[1][0] = __builtin_amdgcn_mfma_f32_16x16x32_bf16(a1, b0, acc[1][0], 0, 0, 0);
        acc[1][1] = __builtin_amdgcn_mfma_f32_16x16x32_bf16(a1, b1, acc[1][1], 0, 0, 0);
        acc[1][2] = __builtin_amdgcn_mfma_f32_16x16x32_bf16(a1, b2, acc[1][2], 0, 0, 0);
        acc[1][3] = __builtin_amdgcn_mfma_f32_16x16x32_bf16(a1, b3, acc[1][3], 0, 0, 0);
    }

    const float epsv = 1.0f + eps[0];
    #pragma unroll
    for (int ta = 0; ta < 2; ++ta) {
        #pragma unroll
        for (int r = 0; r < 4; ++r) {
            int n = n0 + et * 32 + ta * 16 + q * 4 + r;
            if (n < NNODES) {
                #pragma unroll
                for (int tb = 0; tb < 4; ++tb) {
                    int o = nh * 64 + tb * 16 + li;
                    float v = acc[ta][tb][r] + b_self[o]
                            + epsv * neigh[(size_t)n * 128 + o];
                    out[(size_t)n * 128 + o] = v;
                }
            }
        }
    }
}

// ---------------------------------------------------------------------------
extern "C" void kernel_launch(void* const* d_in, const int* in_sizes, int n_in,
                              void* d_out, int out_size, void* d_ws, size_t ws_size,
                              hipStream_t stream) {
    const float* nfeat  = (const float*)d_in[0];
    const float* etype  = (const float*)d_in[1];
    const int*   src    = (const int*)d_in[2];
    const int*   dst    = (const int*)d_in[3];
    const float* W_edge = (const float*)d_in[4];
    const float* W_ne   = (const float*)d_in[5];
    const float* b_ne   = (const float*)d_in[6];
    const float* W_self = (const float*)d_in[7];
    const float* b_self = (const float*)d_in[8];
    const float* eps    = (const float*)d_in[9];
    float* out = (float*)d_out;

    char* ws = (char*)d_ws;
    float* neigh  = (float*)ws;                                  // 50000*128*4 B
    short* WcatB  = (short*)(ws + (size_t)NNODES * 128 * 4);     // 128*160*2 B
    short* WselfB = (short*)(ws + (size_t)NNODES * 128 * 4 + OUT_DIM * KDIM * 2);

    hipMemsetAsync(neigh, 0, (size_t)NNODES * 128 * sizeof(float), stream);
    prep_weights<<<144, 256, 0, stream>>>(W_edge, W_ne, W_self, WcatB, WselfB);
    edge_kernel<<<NEDGES / 64, 256, 0, stream>>>(nfeat, etype, src, dst, b_ne,
                                                 WcatB, neigh);
    node_kernel<<<(NNODES + 63) / 64, 256, 0, stream>>>(nfeat, b_self, eps,
                                                        WselfB, neigh, out);
}